// Round 4
// baseline (2260.828 us; speedup 1.0000x reference)
//
#include <hip/hip_runtime.h>

// Problem constants (from reference)
#define NB   32768
#define NT   200
#define DE   6
#define NIV  8
#define MH   16
#define NH   128
#define DTC  0.01f

// LDS row layout per hidden unit j (stride LSTR=20 floats):
//  [0..13] = W1[j][0..13]   (only columns used by fwd x-part and bwd)
//  [14]    = 2 * sum_k W2[k][j]            (scale)
//  [15]    = alpha_j = b1[j] + bE.W1[j][14:30] + bnu.W1[j][30:46]
//  [16]    = beta_j  = WE . W1[j][14:30]   (coefficient of E)
//  [17]    = gamma_j = Wnu . W1[j][30:46]  (coefficient of nu)
// stride 20 floats = 80 B: the 8 sub-lanes' rows start at banks
// {0,20,8,28,16,4,24,12} -> 8 disjoint 4-bank groups, conflict-free b128s.
#define LSTR 20

__global__ __launch_bounds__(256, 4)
void visco_fused8(const float* __restrict__ e, const float* __restrict__ edot,
                  const float* __restrict__ Ein, const float* __restrict__ nuin,
                  const float* __restrict__ We1, const float* __restrict__ be1,
                  const float* __restrict__ We2,
                  const float* __restrict__ Wd1, const float* __restrict__ bd1,
                  const float* __restrict__ Wd2,
                  const float* __restrict__ WE,  const float* __restrict__ bE,
                  const float* __restrict__ Wnu, const float* __restrict__ bnu,
                  float* __restrict__ out_stress, float* __restrict__ out_xi)
{
    __shared__ float LE[NH * LSTR];
    __shared__ float LD[NH * LSTR];

    const int tid = threadIdx.x;

    // ---- weight-table build: threads 0..127 -> LE row, 128..255 -> LD row ----
    {
        const int j = tid & 127;
        const float* W1 = (tid < NH) ? We1 : Wd1;
        const float* b1 = (tid < NH) ? be1 : bd1;
        float*       L  = (tid < NH) ? LE  : LD;
        const float* row = W1 + j * 46;
        float alpha = b1[j], beta = 0.f, gamma = 0.f;
        #pragma unroll
        for (int k = 0; k < MH; ++k) {
            alpha += bE[k]  * row[14 + k] + bnu[k] * row[30 + k];
            beta  += WE[k]  * row[14 + k];
            gamma += Wnu[k] * row[30 + k];
        }
        #pragma unroll
        for (int i = 0; i < 14; ++i) L[j * LSTR + i] = row[i];
        L[j * LSTR + 14] = (tid < NH) ? (2.0f * (We2[j] + We2[NH + j]))
                                      : (2.0f * Wd2[j]);
        L[j * LSTR + 15] = alpha;
        L[j * LSTR + 16] = beta;
        L[j * LSTR + 17] = gamma;
    }
    __syncthreads();

    // ---- 8 threads per batch element; sub-lane s owns rows j = 8*jj + s ----
    const int gt   = blockIdx.x * 256 + tid;
    const int elem = gt >> 3;
    const int s    = tid & 7;

    const float Ev  = Ein[elem];
    const float nuv = nuin[elem];

    // per-(elem,row) h-chain starting values: alpha + E*beta + nu*gamma
    float baseE[16], baseD[16];
    #pragma unroll
    for (int jj = 0; jj < 16; ++jj) {
        const float* re = &LE[(8 * jj + s) * LSTR];
        const float* rd = &LD[(8 * jj + s) * LSTR];
        baseE[jj] = fmaf(nuv, re[17], fmaf(Ev, re[16], re[15]));
        baseD[jj] = fmaf(nuv, rd[17], fmaf(Ev, rd[16], rd[15]));
    }

    float xi[NIV];
    #pragma unroll
    for (int i = 0; i < NIV; ++i) xi[i] = 0.f;

    const float* ep = e    + (size_t)elem * (NT * DE);
    const float* dp = edot + (size_t)elem * (NT * DE);
    float* sp = out_stress + (size_t)elem * (NT * DE);
    float* xp = out_xi     + (size_t)elem * (NT * NIV);

    // software-prefetched strain inputs (cur = step t, nxt loads t+1)
    float2 ea = *(const float2*)(ep + 0);
    float2 eb = *(const float2*)(ep + 2);
    float2 ec = *(const float2*)(ep + 4);
    float2 da = *(const float2*)(dp + 0);
    float2 db = *(const float2*)(dp + 2);
    float2 dc = *(const float2*)(dp + 4);

    #pragma unroll 1
    for (int t = 0; t < NT; ++t) {
        const int tn = (t + 1 < NT) ? (t + 1) : t;   // clamped prefetch index
        float2 na = *(const float2*)(ep + tn * DE + 0);
        float2 nb = *(const float2*)(ep + tn * DE + 2);
        float2 nc = *(const float2*)(ep + tn * DE + 4);
        float2 ma = *(const float2*)(dp + tn * DE + 0);
        float2 mb = *(const float2*)(dp + tn * DE + 2);
        float2 mc = *(const float2*)(dp + tn * DE + 4);

        // ================= MLP-e gradient: ge[0..13] =================
        float g[14];
        #pragma unroll
        for (int i = 0; i < 14; ++i) g[i] = 0.f;

        #pragma unroll 2
        for (int jj = 0; jj < 16; ++jj) {
            const float* row = &LE[(8 * jj + s) * LSTR];
            float h = baseE[jj];
            h = fmaf(ea.x, row[0],  h);
            h = fmaf(ea.y, row[1],  h);
            h = fmaf(eb.x, row[2],  h);
            h = fmaf(eb.y, row[3],  h);
            h = fmaf(ec.x, row[4],  h);
            h = fmaf(ec.y, row[5],  h);
            h = fmaf(xi[0], row[6],  h);
            h = fmaf(xi[1], row[7],  h);
            h = fmaf(xi[2], row[8],  h);
            h = fmaf(xi[3], row[9],  h);
            h = fmaf(xi[4], row[10], h);
            h = fmaf(xi[5], row[11], h);
            h = fmaf(xi[6], row[12], h);
            h = fmaf(xi[7], row[13], h);
            const float a = fmaxf(h, 0.f) * row[14];
            #pragma unroll
            for (int i = 0; i < 14; ++i) g[i] = fmaf(a, row[i], g[i]);
        }
        // reduce partial gradients across the 8 sub-lanes (lane-group aligned)
        #pragma unroll
        for (int i = 0; i < 14; ++i) {
            g[i] += __shfl_xor(g[i], 1);
            g[i] += __shfl_xor(g[i], 2);
            g[i] += __shfl_xor(g[i], 4);
        }
        // s_eq = g[0..5], d = g[6..13]

        // ========= MLP-d gradient: gd[0..13], input [edot, -d, m] =========
        float q[14];
        #pragma unroll
        for (int i = 0; i < 14; ++i) q[i] = 0.f;

        #pragma unroll 2
        for (int jj = 0; jj < 16; ++jj) {
            const float* row = &LD[(8 * jj + s) * LSTR];
            float h = baseD[jj];
            h = fmaf(da.x, row[0],  h);
            h = fmaf(da.y, row[1],  h);
            h = fmaf(db.x, row[2],  h);
            h = fmaf(db.y, row[3],  h);
            h = fmaf(dc.x, row[4],  h);
            h = fmaf(dc.y, row[5],  h);
            h = fmaf(-g[6],  row[6],  h);
            h = fmaf(-g[7],  row[7],  h);
            h = fmaf(-g[8],  row[8],  h);
            h = fmaf(-g[9],  row[9],  h);
            h = fmaf(-g[10], row[10], h);
            h = fmaf(-g[11], row[11], h);
            h = fmaf(-g[12], row[12], h);
            h = fmaf(-g[13], row[13], h);
            const float a = fmaxf(h, 0.f) * row[14];
            #pragma unroll
            for (int i = 0; i < 14; ++i) q[i] = fmaf(a, row[i], q[i]);
        }
        #pragma unroll
        for (int i = 0; i < 14; ++i) {
            q[i] += __shfl_xor(q[i], 1);
            q[i] += __shfl_xor(q[i], 2);
            q[i] += __shfl_xor(q[i], 4);
        }
        // s_neq = q[0..5], kinetics = q[6..13]

        // ================= outputs (xi written PRE-update) =================
        if (s == 0) {
            float2* o = (float2*)(sp + t * DE);
            o[0] = make_float2(g[0] - q[0], g[1] - q[1]);
            o[1] = make_float2(g[2] - q[2], g[3] - q[3]);
            o[2] = make_float2(g[4] - q[4], g[5] - q[5]);
        } else if (s == 1) {
            *(float4*)(xp + t * NIV)     = make_float4(xi[0], xi[1], xi[2], xi[3]);
        } else if (s == 2) {
            *(float4*)(xp + t * NIV + 4) = make_float4(xi[4], xi[5], xi[6], xi[7]);
        }

        #pragma unroll
        for (int i = 0; i < NIV; ++i) xi[i] = fmaf(DTC, q[6 + i], xi[i]);

        ea = na; eb = nb; ec = nc;
        da = ma; db = mb; dc = mc;
    }
}

extern "C" void kernel_launch(void* const* d_in, const int* in_sizes, int n_in,
                              void* d_out, int out_size, void* d_ws, size_t ws_size,
                              hipStream_t stream) {
    const float* e    = (const float*)d_in[0];
    const float* edot = (const float*)d_in[1];
    const float* E    = (const float*)d_in[2];
    const float* nu   = (const float*)d_in[3];
    const float* We1  = (const float*)d_in[4];
    const float* be1  = (const float*)d_in[5];
    const float* We2  = (const float*)d_in[6];
    /* d_in[7] = be2 (unused by the gradient formula) */
    const float* Wd1  = (const float*)d_in[8];
    const float* bd1  = (const float*)d_in[9];
    const float* Wd2  = (const float*)d_in[10];
    /* d_in[11] = bd2 (unused) */
    const float* WE   = (const float*)d_in[12];
    const float* bE   = (const float*)d_in[13];
    const float* Wnu  = (const float*)d_in[14];
    const float* bnu  = (const float*)d_in[15];

    float* out_stress = (float*)d_out;
    float* out_xi     = out_stress + (size_t)NB * NT * DE;

    const int threads = NB * 8;              // 8 threads per batch element
    dim3 grid(threads / 256), block(256);
    visco_fused8<<<grid, block, 0, stream>>>(e, edot, E, nu, We1, be1, We2,
                                             Wd1, bd1, Wd2, WE, bE, Wnu, bnu,
                                             out_stress, out_xi);
}